// Round 1
// baseline (394.183 us; speedup 1.0000x reference)
//
#include <hip/hip_runtime.h>
#include <hip/hip_bf16.h>

#define TOKENS 2048
#define DIM    1024
#define FDIM   1408
#define NEXP   16
#define NK     (TOKENS * 2)
#define CAP    320

typedef __attribute__((ext_vector_type(4))) float f32x4;
typedef __attribute__((ext_vector_type(8))) short s16x8;
typedef __attribute__((ext_vector_type(4))) short s16x4;

__device__ __forceinline__ short f2bf(float f) {
    unsigned int u = __float_as_uint(f);
    u += 0x7FFFu + ((u >> 16) & 1u);   // RNE
    return (short)(u >> 16);
}
__device__ __forceinline__ float bf2f(short s) {
    return __uint_as_float(((unsigned int)(unsigned short)s) << 16);
}

// ---------------- Router: logits -> softmax -> top2 -> renormalize ----------
__global__ __launch_bounds__(256) void router_kernel(
    const float* __restrict__ x, const float* __restrict__ rw,
    const float* __restrict__ rb, int* __restrict__ idx_flat,
    float* __restrict__ vals_flat)
{
    __shared__ float lg[16][17];
    const int t  = threadIdx.x;
    const int tl = t >> 4;      // token within block
    const int e  = t & 15;      // expert
    const int token = blockIdx.x * 16 + tl;
    const float* xr = x + (size_t)token * DIM;

    float acc = 0.f;
    for (int d4 = 0; d4 < DIM / 4; d4++) {
        float4 xv = *(const float4*)(xr + d4 * 4);
        acc += xv.x * rw[(d4 * 4 + 0) * NEXP + e];
        acc += xv.y * rw[(d4 * 4 + 1) * NEXP + e];
        acc += xv.z * rw[(d4 * 4 + 2) * NEXP + e];
        acc += xv.w * rw[(d4 * 4 + 3) * NEXP + e];
    }
    lg[tl][e] = acc + rb[e];
    __syncthreads();

    if (t < 16) {
        float l[16];
#pragma unroll
        for (int j = 0; j < 16; j++) l[j] = lg[t][j];
        float m = l[0];
#pragma unroll
        for (int j = 1; j < 16; j++) m = fmaxf(m, l[j]);
        float p[16], den = 0.f;
#pragma unroll
        for (int j = 0; j < 16; j++) { p[j] = __expf(l[j] - m); den += p[j]; }
        int i1 = -1; float b1 = -1e30f;
#pragma unroll
        for (int j = 0; j < 16; j++) if (p[j] > b1) { b1 = p[j]; i1 = j; }
        int i2 = -1; float b2 = -1e30f;
#pragma unroll
        for (int j = 0; j < 16; j++) if (j != i1 && p[j] > b2) { b2 = p[j]; i2 = j; }
        float v1 = b1 / den, v2 = b2 / den;
        float s = v1 + v2 + 1e-9f;
        int tok = blockIdx.x * 16 + t;
        idx_flat[tok * 2 + 0] = i1;
        idx_flat[tok * 2 + 1] = i2;
        vals_flat[tok * 2 + 0] = v1 / s;
        vals_flat[tok * 2 + 1] = v2 / s;
    }
}

// ------------- Sequential position scan (1 wave, ballot-based) --------------
__global__ void scan_kernel(const int* __restrict__ idx_flat,
                            const float* __restrict__ vals,
                            int* __restrict__ dst, float* __restrict__ wgt,
                            int* __restrict__ cnt)
{
    const int lane = threadIdx.x;   // 64 threads
    int base[16];
#pragma unroll
    for (int e = 0; e < 16; e++) base[e] = 0;

    for (int c = 0; c < NK / 64; c++) {
        int i = c * 64 + lane;
        int e = idx_flat[i];
        unsigned long long m[16];
#pragma unroll
        for (int ee = 0; ee < 16; ee++) m[ee] = __ballot(e == ee);
        unsigned long long mym = 0ULL; int myb = 0;
#pragma unroll
        for (int ee = 0; ee < 16; ee++) {
            bool sel = (e == ee);
            mym = sel ? m[ee] : mym;
            myb = sel ? base[ee] : myb;
        }
        int pos = myb + (int)__popcll(mym & ((1ULL << lane) - 1ULL));
        bool within = pos < CAP;
        dst[i] = within ? (e * CAP + pos) : -1;
        wgt[i] = within ? vals[i] : 0.f;
#pragma unroll
        for (int ee = 0; ee < 16; ee++) base[ee] += (int)__popcll(m[ee]);
    }
    if (lane < 16) cnt[lane] = base[lane] < CAP ? base[lane] : CAP;
}

// ---------------- x -> bf16 ----------------
__global__ __launch_bounds__(256) void xconv_kernel(const float* __restrict__ x,
                                                    short* __restrict__ xb)
{
    size_t i = (size_t)blockIdx.x * 1024 + (size_t)threadIdx.x * 4;
    float4 v = *(const float4*)(x + i);
    s16x4 o;
    o[0] = f2bf(v.x); o[1] = f2bf(v.y); o[2] = f2bf(v.z); o[3] = f2bf(v.w);
    *(s16x4*)(xb + i) = o;
}

// ---------------- Scatter tokens into per-expert buffers (bf16) -------------
__global__ __launch_bounds__(256) void scatter_kernel(const float* __restrict__ x,
                                                      const int* __restrict__ dst,
                                                      short* __restrict__ ex)
{
    const int i = blockIdx.x;
    const int d0 = dst[i];
    if (d0 < 0) return;
    const int token = i >> 1;
    size_t so = (size_t)token * DIM + (size_t)threadIdx.x * 4;
    float4 v = *(const float4*)(x + so);
    s16x4 o;
    o[0] = f2bf(v.x); o[1] = f2bf(v.y); o[2] = f2bf(v.z); o[3] = f2bf(v.w);
    *(s16x4*)(ex + (size_t)d0 * DIM + (size_t)threadIdx.x * 4) = o;
}

// ---------------- Grouped GEMM: bf16 A x fp32->bf16 B, MFMA 16x16x32 --------
// GATEUP=1: Out = silu(A@B0) * (A@B1), Out bf16 [M][N]
// GATEUP=0: Out = A@B0
// Tile: BM=64, BN=128, BK=32; 4 waves, each 32x64 (2x4 frags)
template <int GATEUP>
__global__ __launch_bounds__(256) void gemm_kernel(
    const short* __restrict__ A, long sA,
    const float* __restrict__ B0, const float* __restrict__ B1, long sB,
    short* __restrict__ Out, long sO,
    const int* __restrict__ cnt, int N, int K)
{
    constexpr int NMAT = GATEUP ? 2 : 1;
    __shared__ short lA[64 * 32];
    __shared__ short lB[NMAT][128 * 40];   // rows padded to 40 shorts (80 B)

    const int g  = blockIdx.z;
    const int m0 = blockIdx.y * 64;
    const int n0 = blockIdx.x * 128;
    if (cnt != nullptr && m0 >= cnt[g]) return;

    const short* Ag = A + (size_t)g * sA + (size_t)m0 * K;
    const float* Bg[NMAT];
    Bg[0] = B0 + (size_t)g * sB;
#pragma unroll
    for (int mat = 1; mat < NMAT; mat++) Bg[mat] = B1 + (size_t)g * sB;
    short* Og = Out + (size_t)g * sO;

    const int tid  = threadIdx.x;
    const int lane = tid & 63;
    const int wid  = tid >> 6;
    const int wr   = wid >> 1, wc = wid & 1;
    const int ln   = lane & 15, kg = lane >> 4;

    // A staging: thread loads 8 contiguous bf16 (16B)
    const short* ap = Ag + (size_t)(tid >> 2) * K + (size_t)(tid & 3) * 8;
    short* lAw = lA + tid * 8;

    // B staging: thread owns one col n, 16 k-rows (scalar coalesced loads)
    const int bn = tid & 127, bh = tid >> 7;
    const float* bp[NMAT];
#pragma unroll
    for (int mat = 0; mat < NMAT; mat++)
        bp[mat] = Bg[mat] + (size_t)(bh * 16) * N + n0 + bn;
    short* lBw = &lB[0][0] + bn * 40 + bh * 16;

    const short* lAr = lA + (wr * 32 + ln) * 32 + kg * 8;
    const short* lBr = &lB[0][0] + (wc * 64 + ln) * 40 + kg * 8;

    f32x4 acc[NMAT][2][4] = {};

    const int ksteps = K / 32;
    for (int ks = 0; ks < ksteps; ks++) {
        s16x8 av = *(const s16x8*)ap;
        float bv[NMAT][16];
#pragma unroll
        for (int mat = 0; mat < NMAT; mat++)
#pragma unroll
            for (int j = 0; j < 16; j++) bv[mat][j] = bp[mat][(size_t)j * N];

        __syncthreads();   // previous iteration's frag reads done
        *(s16x8*)lAw = av;
#pragma unroll
        for (int mat = 0; mat < NMAT; mat++) {
            s16x8 p0, p1;
#pragma unroll
            for (int j = 0; j < 8; j++) {
                p0[j] = f2bf(bv[mat][j]);
                p1[j] = f2bf(bv[mat][8 + j]);
            }
            *(s16x8*)(lBw + mat * 128 * 40)     = p0;
            *(s16x8*)(lBw + mat * 128 * 40 + 8) = p1;
        }
        __syncthreads();

        s16x8 af0 = *(const s16x8*)(lAr);
        s16x8 af1 = *(const s16x8*)(lAr + 16 * 32);
#pragma unroll
        for (int nf = 0; nf < 4; nf++) {
#pragma unroll
            for (int mat = 0; mat < NMAT; mat++) {
                s16x8 bf = *(const s16x8*)(lBr + mat * 128 * 40 + nf * 16 * 40);
                acc[mat][0][nf] = __builtin_amdgcn_mfma_f32_16x16x32_bf16(af0, bf, acc[mat][0][nf], 0, 0, 0);
                acc[mat][1][nf] = __builtin_amdgcn_mfma_f32_16x16x32_bf16(af1, bf, acc[mat][1][nf], 0, 0, 0);
            }
        }
        ap += 32;
#pragma unroll
        for (int mat = 0; mat < NMAT; mat++) bp[mat] += (size_t)32 * N;
    }

    // Epilogue: C/D layout col=lane&15, row=(lane>>4)*4+j  [m89-verified]
#pragma unroll
    for (int m = 0; m < 2; m++) {
#pragma unroll
        for (int nf = 0; nf < 4; nf++) {
            int row = m0 + wr * 32 + m * 16 + kg * 4;
            int col = n0 + wc * 64 + nf * 16 + ln;
#pragma unroll
            for (int j = 0; j < 4; j++) {
                float v;
                if (GATEUP) {
                    float gv = acc[0][m][nf][j];
                    float uv = acc[NMAT - 1][m][nf][j];
                    v = gv / (1.f + __expf(-gv)) * uv;
                } else {
                    v = acc[0][m][nf][j];
                }
                Og[(size_t)(row + j) * N + col] = f2bf(v);
            }
        }
    }
}

// ---------------- Combine: out = x + shared + sum_k w_k * expert_row --------
__global__ __launch_bounds__(256) void combine_kernel(
    const float* __restrict__ x, const short* __restrict__ shout,
    const short* __restrict__ eout, const int* __restrict__ dst,
    const float* __restrict__ wgt, float* __restrict__ out)
{
    const int t = blockIdx.x;
    const int d = threadIdx.x * 4;
    size_t o = (size_t)t * DIM + d;
    float4 xv = *(const float4*)(x + o);
    s16x4 sv = *(const s16x4*)(shout + o);
    float r0 = xv.x + bf2f(sv[0]);
    float r1 = xv.y + bf2f(sv[1]);
    float r2 = xv.z + bf2f(sv[2]);
    float r3 = xv.w + bf2f(sv[3]);
#pragma unroll
    for (int k = 0; k < 2; k++) {
        int di = dst[t * 2 + k];
        if (di >= 0) {
            float w = wgt[t * 2 + k];
            s16x4 ev = *(const s16x4*)(eout + (size_t)di * DIM + d);
            r0 += w * bf2f(ev[0]);
            r1 += w * bf2f(ev[1]);
            r2 += w * bf2f(ev[2]);
            r3 += w * bf2f(ev[3]);
        }
    }
    float4 rv = {r0, r1, r2, r3};
    *(float4*)(out + o) = rv;
}

extern "C" void kernel_launch(void* const* d_in, const int* in_sizes, int n_in,
                              void* d_out, int out_size, void* d_ws, size_t ws_size,
                              hipStream_t stream)
{
    const float* x   = (const float*)d_in[0];
    const float* rw  = (const float*)d_in[1];
    const float* rb  = (const float*)d_in[2];
    const float* wg  = (const float*)d_in[3];
    const float* wu  = (const float*)d_in[4];
    const float* wd  = (const float*)d_in[5];
    const float* swg = (const float*)d_in[6];
    const float* swu = (const float*)d_in[7];
    const float* swd = (const float*)d_in[8];
    float* out = (float*)d_out;

    char* wp = (char*)d_ws;
    auto alloc = [&](size_t b) { char* p = wp; wp += (b + 255) & ~(size_t)255; return p; };
    int*   idx_flat = (int*)alloc((size_t)NK * 4);
    float* vals     = (float*)alloc((size_t)NK * 4);
    int*   dst      = (int*)alloc((size_t)NK * 4);
    float* wgt      = (float*)alloc((size_t)NK * 4);
    int*   cnt      = (int*)alloc(64);
    short* xb       = (short*)alloc((size_t)TOKENS * DIM * 2);
    short* ex       = (short*)alloc((size_t)NEXP * CAP * DIM * 2);
    short* acte     = (short*)alloc((size_t)NEXP * CAP * FDIM * 2);
    short* acts     = (short*)alloc((size_t)TOKENS * FDIM * 2);
    short* eout     = (short*)alloc((size_t)NEXP * CAP * DIM * 2);
    short* shout    = (short*)alloc((size_t)TOKENS * DIM * 2);

    router_kernel<<<TOKENS / 16, 256, 0, stream>>>(x, rw, rb, idx_flat, vals);
    scan_kernel<<<1, 64, 0, stream>>>(idx_flat, vals, dst, wgt, cnt);
    xconv_kernel<<<(TOKENS * DIM) / 1024, 256, 0, stream>>>(x, xb);
    scatter_kernel<<<NK, 256, 0, stream>>>(x, dst, ex);

    // Expert gate+up fused (-> act bf16), then shared
    gemm_kernel<1><<<dim3(FDIM / 128, CAP / 64, NEXP), 256, 0, stream>>>(
        ex, (long)CAP * DIM, wg, wu, (long)DIM * FDIM, acte, (long)CAP * FDIM,
        cnt, FDIM, DIM);
    gemm_kernel<1><<<dim3(FDIM / 128, TOKENS / 64, 1), 256, 0, stream>>>(
        xb, 0L, swg, swu, 0L, acts, 0L, nullptr, FDIM, DIM);

    // Down projections
    gemm_kernel<0><<<dim3(DIM / 128, CAP / 64, NEXP), 256, 0, stream>>>(
        acte, (long)CAP * FDIM, wd, nullptr, (long)FDIM * DIM, eout,
        (long)CAP * DIM, cnt, DIM, FDIM);
    gemm_kernel<0><<<dim3(DIM / 128, TOKENS / 64, 1), 256, 0, stream>>>(
        acts, 0L, swd, nullptr, 0L, shout, 0L, nullptr, DIM, FDIM);

    combine_kernel<<<TOKENS, 256, 0, stream>>>(x, shout, eout, dst, wgt, out);
}

// Round 2
// 382.531 us; speedup vs baseline: 1.0305x; 1.0305x over previous
//
#include <hip/hip_runtime.h>
#include <hip/hip_bf16.h>

#define TOKENS 2048
#define DIM    1024
#define FDIM   1408
#define NEXP   16
#define NK     (TOKENS * 2)
#define CAP    320

typedef __attribute__((ext_vector_type(4))) float f32x4;
typedef __attribute__((ext_vector_type(8))) short s16x8;
typedef __attribute__((ext_vector_type(4))) short s16x4;

__device__ __forceinline__ short f2bf(float f) {
    unsigned int u = __float_as_uint(f);
    u += 0x7FFFu + ((u >> 16) & 1u);   // RNE
    return (short)(u >> 16);
}
__device__ __forceinline__ float bf2f(short s) {
    return __uint_as_float(((unsigned int)(unsigned short)s) << 16);
}

#define GLDS16(gp, lp) __builtin_amdgcn_global_load_lds(                     \
    (const __attribute__((address_space(1))) unsigned int*)(gp),             \
    (__attribute__((address_space(3))) unsigned int*)(lp), 16, 0, 0)

// ---------------- Router: logits -> softmax -> top2 -> renormalize ----------
__global__ __launch_bounds__(256) void router_kernel(
    const float* __restrict__ x, const float* __restrict__ rw,
    const float* __restrict__ rb, int* __restrict__ idx_flat,
    float* __restrict__ vals_flat)
{
    __shared__ float lg[16][17];
    const int t  = threadIdx.x;
    const int tl = t >> 4;      // token within block
    const int e  = t & 15;      // expert
    const int token = blockIdx.x * 16 + tl;
    const float* xr = x + (size_t)token * DIM;

    float acc = 0.f;
    for (int d4 = 0; d4 < DIM / 4; d4++) {
        float4 xv = *(const float4*)(xr + d4 * 4);
        acc += xv.x * rw[(d4 * 4 + 0) * NEXP + e];
        acc += xv.y * rw[(d4 * 4 + 1) * NEXP + e];
        acc += xv.z * rw[(d4 * 4 + 2) * NEXP + e];
        acc += xv.w * rw[(d4 * 4 + 3) * NEXP + e];
    }
    lg[tl][e] = acc + rb[e];
    __syncthreads();

    if (t < 16) {
        float l[16];
#pragma unroll
        for (int j = 0; j < 16; j++) l[j] = lg[t][j];
        float m = l[0];
#pragma unroll
        for (int j = 1; j < 16; j++) m = fmaxf(m, l[j]);
        float p[16], den = 0.f;
#pragma unroll
        for (int j = 0; j < 16; j++) { p[j] = __expf(l[j] - m); den += p[j]; }
        int i1 = -1; float b1 = -1e30f;
#pragma unroll
        for (int j = 0; j < 16; j++) if (p[j] > b1) { b1 = p[j]; i1 = j; }
        int i2 = -1; float b2 = -1e30f;
#pragma unroll
        for (int j = 0; j < 16; j++) if (j != i1 && p[j] > b2) { b2 = p[j]; i2 = j; }
        float v1 = b1 / den, v2 = b2 / den;
        float s = v1 + v2 + 1e-9f;
        int tok = blockIdx.x * 16 + t;
        idx_flat[tok * 2 + 0] = i1;
        idx_flat[tok * 2 + 1] = i2;
        vals_flat[tok * 2 + 0] = v1 / s;
        vals_flat[tok * 2 + 1] = v2 / s;
    }
}

// ------------- Sequential position scan (1 wave, ballot-based) --------------
__global__ void scan_kernel(const int* __restrict__ idx_flat,
                            const float* __restrict__ vals,
                            int* __restrict__ dst, float* __restrict__ wgt,
                            int* __restrict__ cnt)
{
    const int lane = threadIdx.x;   // 64 threads
    int base[16];
#pragma unroll
    for (int e = 0; e < 16; e++) base[e] = 0;

    for (int c = 0; c < NK / 64; c++) {
        int i = c * 64 + lane;
        int e = idx_flat[i];
        unsigned long long m[16];
#pragma unroll
        for (int ee = 0; ee < 16; ee++) m[ee] = __ballot(e == ee);
        unsigned long long mym = 0ULL; int myb = 0;
#pragma unroll
        for (int ee = 0; ee < 16; ee++) {
            bool sel = (e == ee);
            mym = sel ? m[ee] : mym;
            myb = sel ? base[ee] : myb;
        }
        int pos = myb + (int)__popcll(mym & ((1ULL << lane) - 1ULL));
        bool within = pos < CAP;
        dst[i] = within ? (e * CAP + pos) : -1;
        wgt[i] = within ? vals[i] : 0.f;
#pragma unroll
        for (int ee = 0; ee < 16; ee++) base[ee] += (int)__popcll(m[ee]);
    }
    if (lane < 16) cnt[lane] = base[lane] < CAP ? base[lane] : CAP;
}

// ---------------- x -> bf16 ----------------
__global__ __launch_bounds__(256) void xconv_kernel(const float* __restrict__ x,
                                                    short* __restrict__ xb)
{
    size_t i = (size_t)blockIdx.x * 1024 + (size_t)threadIdx.x * 4;
    float4 v = *(const float4*)(x + i);
    s16x4 o;
    o[0] = f2bf(v.x); o[1] = f2bf(v.y); o[2] = f2bf(v.z); o[3] = f2bf(v.w);
    *(s16x4*)(xb + i) = o;
}

// ---------------- Scatter tokens into per-expert buffers (bf16) -------------
__global__ __launch_bounds__(256) void scatter_kernel(const float* __restrict__ x,
                                                      const int* __restrict__ dst,
                                                      short* __restrict__ ex)
{
    const int i = blockIdx.x;
    const int d0 = dst[i];
    if (d0 < 0) return;
    const int token = i >> 1;
    size_t so = (size_t)token * DIM + (size_t)threadIdx.x * 4;
    float4 v = *(const float4*)(x + so);
    s16x4 o;
    o[0] = f2bf(v.x); o[1] = f2bf(v.y); o[2] = f2bf(v.z); o[3] = f2bf(v.w);
    *(s16x4*)(ex + (size_t)d0 * DIM + (size_t)threadIdx.x * 4) = o;
}

// -------- Weight convert+transpose: fp32 [K][N] -> bf16 [N][K] --------------
// grid: (N/64, K/64, nmats), 256 threads
__global__ __launch_bounds__(256) void wtrans_kernel(
    const float* __restrict__ in, short* __restrict__ out, int K, int N)
{
    __shared__ float tile[64][65];
    const int mat = blockIdx.z;
    const int k0 = blockIdx.y * 64;
    const int n0 = blockIdx.x * 64;
    const float* inp = in + (size_t)mat * K * N;
    short* outp = out + (size_t)mat * K * N;
    const int t  = threadIdx.x;
    const int rr = t >> 4;           // 0..15
    const int cc = (t & 15) * 4;     // 0..60
#pragma unroll
    for (int i = 0; i < 4; i++) {
        int k = rr + i * 16;
        float4 v = *(const float4*)(inp + (size_t)(k0 + k) * N + n0 + cc);
        tile[k][cc + 0] = v.x; tile[k][cc + 1] = v.y;
        tile[k][cc + 2] = v.z; tile[k][cc + 3] = v.w;
    }
    __syncthreads();
    const int nr = t >> 2;           // 0..63
    const int kc = (t & 3) * 16;     // 0,16,32,48
    s16x8 o0, o1;
#pragma unroll
    for (int j = 0; j < 8; j++) {
        o0[j] = f2bf(tile[kc + j][nr]);
        o1[j] = f2bf(tile[kc + 8 + j][nr]);
    }
    short* op = outp + (size_t)(n0 + nr) * K + k0 + kc;
    *(s16x8*)(op)     = o0;
    *(s16x8*)(op + 8) = o1;
}

// ---------------- Grouped GEMM: bf16 x bf16(B^T), MFMA 16x16x32 -------------
// A [G][M][K] bf16, B^T [G][N][K] bf16. GATEUP=1: Out = silu(A@B0)*(A@B1).
// Tile BM=64 BN=128 BK=32; 4 waves (each 32x64); dbuf LDS + global_load_lds.
template <int GATEUP>
__global__ __launch_bounds__(256) void gemm_kernel(
    const short* __restrict__ A, long sA,
    const short* __restrict__ B0, const short* __restrict__ B1, long sB,
    short* __restrict__ Out, long sO,
    const int* __restrict__ cnt, int N, int K)
{
    constexpr int NMAT = GATEUP ? 2 : 1;
    constexpr int BK = 32;
    __shared__ short lA[2][64 * BK];           // 4 KB x2
    __shared__ short lB[2][NMAT][128 * BK];    // 8 KB xNMAT x2

    const int g  = blockIdx.z;
    const int m0 = blockIdx.y * 64;
    const int n0 = blockIdx.x * 128;
    if (cnt != nullptr && m0 >= cnt[g]) return;

    const int tid  = threadIdx.x;
    const int w    = tid >> 6;
    const int lane = tid & 63;
    const int wr = w >> 1, wc = w & 1;
    const int ln = lane & 15, kg = lane >> 4;

    const short* Ag = A + (size_t)g * sA + (size_t)m0 * K;
    const short* BT[NMAT];
    BT[0] = B0 + (size_t)g * sB + (size_t)n0 * K;
#pragma unroll
    for (int mat = 1; mat < NMAT; mat++)
        BT[mat] = B1 + (size_t)g * sB + (size_t)n0 * K;
    short* Og = Out + (size_t)g * sO;

    // staging: thread covers linear LDS shorts [tid*8, tid*8+8)
    const int arow = tid >> 2, acol = (tid & 3) * 8;      // 64x32 / chunk of 128x32
    const short* aSrc = Ag + (size_t)arow * K + acol;
    const short* bSrc[NMAT][2];
#pragma unroll
    for (int mat = 0; mat < NMAT; mat++) {
        bSrc[mat][0] = BT[mat] + (size_t)arow * K + acol;
        bSrc[mat][1] = BT[mat] + (size_t)(arow + 64) * K + acol;
    }

    f32x4 acc[NMAT][2][4] = {};
    const int ksteps = K / BK;

    // wave-uniform LDS dest bases: wave w covers 1024 B (512 shorts) per instr
    const int wofs = w * 512;

    // frag read offsets (shorts)
    const int aOff0 = (wr * 32 + ln) * BK + kg * 8;
    const int aOff1 = (wr * 32 + 16 + ln) * BK + kg * 8;
    const int bBase = (wc * 64 + ln) * BK + kg * 8;

#define STAGE(buf, ks)                                                        \
    do {                                                                      \
        const size_t ko = (size_t)(ks) * BK;                                  \
        GLDS16(aSrc + ko, &lA[buf][wofs]);                                    \
        _Pragma("unroll")                                                     \
        for (int mat = 0; mat < NMAT; mat++) {                                \
            GLDS16(bSrc[mat][0] + ko, &lB[buf][mat][wofs]);                   \
            GLDS16(bSrc[mat][1] + ko, &lB[buf][mat][2048 + wofs]);            \
        }                                                                     \
    } while (0)

    STAGE(0, 0);
    __syncthreads();

    int cur = 0;
    for (int ks = 0; ks < ksteps; ks++) {
        if (ks + 1 < ksteps) STAGE(cur ^ 1, ks + 1);
        s16x8 af0 = *(const s16x8*)&lA[cur][aOff0];
        s16x8 af1 = *(const s16x8*)&lA[cur][aOff1];
#pragma unroll
        for (int nf = 0; nf < 4; nf++) {
#pragma unroll
            for (int mat = 0; mat < NMAT; mat++) {
                s16x8 bf = *(const s16x8*)&lB[cur][mat][bBase + nf * 16 * BK];
                acc[mat][0][nf] = __builtin_amdgcn_mfma_f32_16x16x32_bf16(af0, bf, acc[mat][0][nf], 0, 0, 0);
                acc[mat][1][nf] = __builtin_amdgcn_mfma_f32_16x16x32_bf16(af1, bf, acc[mat][1][nf], 0, 0, 0);
            }
        }
        __syncthreads();
        cur ^= 1;
    }
#undef STAGE

    // Epilogue: C/D layout col=lane&15, row=(lane>>4)*4+j  [m89-verified]
#pragma unroll
    for (int m = 0; m < 2; m++) {
#pragma unroll
        for (int nf = 0; nf < 4; nf++) {
            int row = m0 + wr * 32 + m * 16 + kg * 4;
            int col = n0 + wc * 64 + nf * 16 + ln;
#pragma unroll
            for (int j = 0; j < 4; j++) {
                float v;
                if (GATEUP) {
                    float gv = acc[0][m][nf][j];
                    float uv = acc[NMAT - 1][m][nf][j];
                    v = gv / (1.f + __expf(-gv)) * uv;
                } else {
                    v = acc[0][m][nf][j];
                }
                Og[(size_t)(row + j) * N + col] = f2bf(v);
            }
        }
    }
}

// ---------------- Combine: out = x + shared + sum_k w_k * expert_row --------
__global__ __launch_bounds__(256) void combine_kernel(
    const float* __restrict__ x, const short* __restrict__ shout,
    const short* __restrict__ eout, const int* __restrict__ dst,
    const float* __restrict__ wgt, float* __restrict__ out)
{
    const int t = blockIdx.x;
    const int d = threadIdx.x * 4;
    size_t o = (size_t)t * DIM + d;
    float4 xv = *(const float4*)(x + o);
    s16x4 sv = *(const s16x4*)(shout + o);
    float r0 = xv.x + bf2f(sv[0]);
    float r1 = xv.y + bf2f(sv[1]);
    float r2 = xv.z + bf2f(sv[2]);
    float r3 = xv.w + bf2f(sv[3]);
#pragma unroll
    for (int k = 0; k < 2; k++) {
        int di = dst[t * 2 + k];
        if (di >= 0) {
            float w = wgt[t * 2 + k];
            s16x4 ev = *(const s16x4*)(eout + (size_t)di * DIM + d);
            r0 += w * bf2f(ev[0]);
            r1 += w * bf2f(ev[1]);
            r2 += w * bf2f(ev[2]);
            r3 += w * bf2f(ev[3]);
        }
    }
    float4 rv = {r0, r1, r2, r3};
    *(float4*)(out + o) = rv;
}

extern "C" void kernel_launch(void* const* d_in, const int* in_sizes, int n_in,
                              void* d_out, int out_size, void* d_ws, size_t ws_size,
                              hipStream_t stream)
{
    const float* x   = (const float*)d_in[0];
    const float* rw  = (const float*)d_in[1];
    const float* rb  = (const float*)d_in[2];
    const float* wg  = (const float*)d_in[3];
    const float* wu  = (const float*)d_in[4];
    const float* wd  = (const float*)d_in[5];
    const float* swg = (const float*)d_in[6];
    const float* swu = (const float*)d_in[7];
    const float* swd = (const float*)d_in[8];
    float* out = (float*)d_out;

    char* wp = (char*)d_ws;
    auto alloc = [&](size_t b) { char* p = wp; wp += (b + 255) & ~(size_t)255; return p; };
    int*   idx_flat = (int*)alloc((size_t)NK * 4);
    float* vals     = (float*)alloc((size_t)NK * 4);
    int*   dst      = (int*)alloc((size_t)NK * 4);
    float* wgt      = (float*)alloc((size_t)NK * 4);
    int*   cnt      = (int*)alloc(64);
    short* xb       = (short*)alloc((size_t)TOKENS * DIM * 2);
    short* ex       = (short*)alloc((size_t)NEXP * CAP * DIM * 2);
    short* acte     = (short*)alloc((size_t)NEXP * CAP * FDIM * 2);
    short* acts     = (short*)alloc((size_t)TOKENS * FDIM * 2);
    short* eout     = (short*)alloc((size_t)NEXP * CAP * DIM * 2);
    short* shout    = (short*)alloc((size_t)TOKENS * DIM * 2);
    short* wgT      = (short*)alloc((size_t)NEXP * DIM * FDIM * 2);
    short* wuT      = (short*)alloc((size_t)NEXP * DIM * FDIM * 2);
    short* wdT      = (short*)alloc((size_t)NEXP * DIM * FDIM * 2);
    short* swgT     = (short*)alloc((size_t)DIM * FDIM * 2);
    short* swuT     = (short*)alloc((size_t)DIM * FDIM * 2);
    short* swdT     = (short*)alloc((size_t)DIM * FDIM * 2);

    // Weight conversion: fp32 [K][N] -> bf16 [N][K]
    wtrans_kernel<<<dim3(FDIM / 64, DIM / 64, NEXP), 256, 0, stream>>>(wg,  wgT,  DIM,  FDIM);
    wtrans_kernel<<<dim3(FDIM / 64, DIM / 64, NEXP), 256, 0, stream>>>(wu,  wuT,  DIM,  FDIM);
    wtrans_kernel<<<dim3(DIM / 64, FDIM / 64, NEXP), 256, 0, stream>>>(wd,  wdT,  FDIM, DIM);
    wtrans_kernel<<<dim3(FDIM / 64, DIM / 64, 1),    256, 0, stream>>>(swg, swgT, DIM,  FDIM);
    wtrans_kernel<<<dim3(FDIM / 64, DIM / 64, 1),    256, 0, stream>>>(swu, swuT, DIM,  FDIM);
    wtrans_kernel<<<dim3(DIM / 64, FDIM / 64, 1),    256, 0, stream>>>(swd, swdT, FDIM, DIM);

    router_kernel<<<TOKENS / 16, 256, 0, stream>>>(x, rw, rb, idx_flat, vals);
    scan_kernel<<<1, 64, 0, stream>>>(idx_flat, vals, dst, wgt, cnt);
    xconv_kernel<<<(TOKENS * DIM) / 1024, 256, 0, stream>>>(x, xb);
    scatter_kernel<<<NK, 256, 0, stream>>>(x, dst, ex);

    // Expert gate+up fused (-> acte bf16), then shared
    gemm_kernel<1><<<dim3(FDIM / 128, CAP / 64, NEXP), 256, 0, stream>>>(
        ex, (long)CAP * DIM, wgT, wuT, (long)DIM * FDIM, acte, (long)CAP * FDIM,
        cnt, FDIM, DIM);
    gemm_kernel<1><<<dim3(FDIM / 128, TOKENS / 64, 1), 256, 0, stream>>>(
        xb, 0L, swgT, swuT, 0L, acts, 0L, nullptr, FDIM, DIM);

    // Down projections
    gemm_kernel<0><<<dim3(DIM / 128, CAP / 64, NEXP), 256, 0, stream>>>(
        acte, (long)CAP * FDIM, wdT, nullptr, (long)DIM * FDIM, eout,
        (long)CAP * DIM, cnt, DIM, FDIM);
    gemm_kernel<0><<<dim3(DIM / 128, TOKENS / 64, 1), 256, 0, stream>>>(
        acts, 0L, swdT, nullptr, 0L, shout, 0L, nullptr, DIM, FDIM);

    combine_kernel<<<TOKENS, 256, 0, stream>>>(x, shout, eout, dst, wgt, out);
}

// Round 3
// 312.560 us; speedup vs baseline: 1.2611x; 1.2239x over previous
//
#include <hip/hip_runtime.h>
#include <hip/hip_bf16.h>

#define TOKENS 2048
#define DIM    1024
#define FDIM   1408
#define NEXP   16
#define NK     (TOKENS * 2)
#define CAP    320
#define RPAD   384          // padded rows per expert (3 x 128)

typedef __attribute__((ext_vector_type(4))) float f32x4;
typedef __attribute__((ext_vector_type(8))) short s16x8;
typedef __attribute__((ext_vector_type(4))) short s16x4;

__device__ __forceinline__ short f2bf(float f) {
    unsigned int u = __float_as_uint(f);
    u += 0x7FFFu + ((u >> 16) & 1u);   // RNE
    return (short)(u >> 16);
}
__device__ __forceinline__ float bf2f(short s) {
    return __uint_as_float(((unsigned int)(unsigned short)s) << 16);
}

#define GLDS16(gp, lp) __builtin_amdgcn_global_load_lds(                     \
    (const __attribute__((address_space(1))) unsigned int*)(gp),             \
    (__attribute__((address_space(3))) unsigned int*)(lp), 16, 0, 0)

// ---------------- Router: logits -> softmax -> top2 -> renormalize ----------
__global__ __launch_bounds__(256) void router_kernel(
    const float* __restrict__ x, const float* __restrict__ rw,
    const float* __restrict__ rb, int* __restrict__ idx_flat,
    float* __restrict__ vals_flat)
{
    __shared__ float lg[16][17];
    const int t  = threadIdx.x;
    const int tl = t >> 4;
    const int e  = t & 15;
    const int token = blockIdx.x * 16 + tl;
    const float* xr = x + (size_t)token * DIM;

    float acc = 0.f;
    for (int d4 = 0; d4 < DIM / 4; d4++) {
        float4 xv = *(const float4*)(xr + d4 * 4);
        acc += xv.x * rw[(d4 * 4 + 0) * NEXP + e];
        acc += xv.y * rw[(d4 * 4 + 1) * NEXP + e];
        acc += xv.z * rw[(d4 * 4 + 2) * NEXP + e];
        acc += xv.w * rw[(d4 * 4 + 3) * NEXP + e];
    }
    lg[tl][e] = acc + rb[e];
    __syncthreads();

    if (t < 16) {
        float l[16];
#pragma unroll
        for (int j = 0; j < 16; j++) l[j] = lg[t][j];
        float m = l[0];
#pragma unroll
        for (int j = 1; j < 16; j++) m = fmaxf(m, l[j]);
        float p[16], den = 0.f;
#pragma unroll
        for (int j = 0; j < 16; j++) { p[j] = __expf(l[j] - m); den += p[j]; }
        int i1 = -1; float b1 = -1e30f;
#pragma unroll
        for (int j = 0; j < 16; j++) if (p[j] > b1) { b1 = p[j]; i1 = j; }
        int i2 = -1; float b2 = -1e30f;
#pragma unroll
        for (int j = 0; j < 16; j++) if (j != i1 && p[j] > b2) { b2 = p[j]; i2 = j; }
        float v1 = b1 / den, v2 = b2 / den;
        float s = v1 + v2 + 1e-9f;
        int tok = blockIdx.x * 16 + t;
        idx_flat[tok * 2 + 0] = i1;
        idx_flat[tok * 2 + 1] = i2;
        vals_flat[tok * 2 + 0] = v1 / s;
        vals_flat[tok * 2 + 1] = v2 / s;
    }
}

// ------------- Sequential position scan (1 wave, ballot-based) --------------
// dst = e*RPAD + pos (row in padded concatenated buffers), -1 if dropped.
__global__ void scan_kernel(const int* __restrict__ idx_flat,
                            const float* __restrict__ vals,
                            int* __restrict__ dst, float* __restrict__ wgt,
                            int* __restrict__ cnt)
{
    const int lane = threadIdx.x;   // 64 threads
    int base[16];
#pragma unroll
    for (int e = 0; e < 16; e++) base[e] = 0;

    for (int c = 0; c < NK / 64; c++) {
        int i = c * 64 + lane;
        int e = idx_flat[i];
        unsigned long long m[16];
#pragma unroll
        for (int ee = 0; ee < 16; ee++) m[ee] = __ballot(e == ee);
        unsigned long long mym = 0ULL; int myb = 0;
#pragma unroll
        for (int ee = 0; ee < 16; ee++) {
            bool sel = (e == ee);
            mym = sel ? m[ee] : mym;
            myb = sel ? base[ee] : myb;
        }
        int pos = myb + (int)__popcll(mym & ((1ULL << lane) - 1ULL));
        bool within = pos < CAP;
        dst[i] = within ? (e * RPAD + pos) : -1;
        wgt[i] = within ? vals[i] : 0.f;
#pragma unroll
        for (int ee = 0; ee < 16; ee++) base[ee] += (int)__popcll(m[ee]);
    }
    if (lane < 16) cnt[lane] = base[lane] < CAP ? base[lane] : CAP;
}

// ------- Weight chunk-reorder: fp32 [K][N] -> bf16 [K/8][N][8] --------------
// grid: (N/128, K/16, mats), 256 threads (2 slabs per block)
__global__ __launch_bounds__(256) void wchunk_kernel(
    const float* __restrict__ in, short* __restrict__ out, int K, int N)
{
    const int mat  = blockIdx.z;
    const int slab = blockIdx.y * 2 + (threadIdx.x >> 7);
    const int n    = blockIdx.x * 128 + (threadIdx.x & 127);
    const float* src = in + (size_t)mat * K * N + (size_t)slab * 8 * N + n;
    short* dstp = out + (size_t)mat * K * N + (size_t)slab * N * 8 + (size_t)n * 8;
    s16x8 o;
#pragma unroll
    for (int j = 0; j < 8; j++) o[j] = f2bf(src[(size_t)j * N]);
    *(s16x8*)dstp = o;
}

// -------- x -> bf16 chunk layout [DIM/8][TOKENS][8] -------------------------
__global__ __launch_bounds__(128) void xconv_kernel(const float* __restrict__ x,
                                                    short* __restrict__ xb)
{
    const int token = blockIdx.x;
    const int c = threadIdx.x;     // k-chunk 0..127
    const float* src = x + (size_t)token * DIM + c * 8;
    float4 v0 = *(const float4*)(src);
    float4 v1 = *(const float4*)(src + 4);
    s16x8 o;
    o[0] = f2bf(v0.x); o[1] = f2bf(v0.y); o[2] = f2bf(v0.z); o[3] = f2bf(v0.w);
    o[4] = f2bf(v1.x); o[5] = f2bf(v1.y); o[6] = f2bf(v1.z); o[7] = f2bf(v1.w);
    *(s16x8*)(xb + (size_t)c * (TOKENS * 8) + (size_t)token * 8) = o;
}

// ---- Scatter token into expert buffer, chunk layout [K/8][RPAD][8] ---------
__global__ __launch_bounds__(128) void scatter_kernel(
    const float* __restrict__ x, const int* __restrict__ dst,
    const int* __restrict__ idx_flat, short* __restrict__ ex)
{
    const int i = blockIdx.x;
    const int d0 = dst[i];
    if (d0 < 0) return;
    const int e = idx_flat[i];
    const int pos = d0 - e * RPAD;
    const int token = i >> 1;
    const int c = threadIdx.x;     // k-chunk 0..127
    const float* src = x + (size_t)token * DIM + c * 8;
    float4 v0 = *(const float4*)(src);
    float4 v1 = *(const float4*)(src + 4);
    s16x8 o;
    o[0] = f2bf(v0.x); o[1] = f2bf(v0.y); o[2] = f2bf(v0.z); o[3] = f2bf(v0.w);
    o[4] = f2bf(v1.x); o[5] = f2bf(v1.y); o[6] = f2bf(v1.z); o[7] = f2bf(v1.w);
    *(s16x8*)(ex + (size_t)e * (DIM * RPAD) + (size_t)c * (RPAD * 8) +
              (size_t)pos * 8) = o;
}

// ---------------- Grouped GEMM, depth-3 counted-vmcnt pipeline --------------
// A: chunk layout [K/8][aRpad][8] bf16 (per expert stride aStride)
// B: chunk layout [K/8][N][8] bf16  (= W^T fragments; per expert stride bStride)
// NMAT=2: Out = silu(A@B0)*(A@B1) stored CHUNK layout [N/8][oRpad][8]
// NMAT=1: Out = A@B0 stored canonical [row][N]
// Tile 128x128(xNMAT), BK=32, 4 waves (2x2), each 64x64 per mat.
template <int NMAT>
__global__ __launch_bounds__(256, 2) void gemm_kernel(
    const short* __restrict__ A, long aStride, int aRpad,
    const short* __restrict__ B0, const short* __restrict__ B1, long bStride,
    short* __restrict__ Out, long oStride, int oRpad,
    const int* __restrict__ cnt, int Mb, int Nb, int N, int K)
{
    constexpr int BUFS = 4096 * (1 + NMAT);     // shorts per pipeline buffer
    __shared__ short lds[3 * BUFS];

    // XCD-aware swizzle (grid % 8 == 0), m fastest -> same-XCD blocks share B
    const int nwg = gridDim.x;
    const int cpx = nwg >> 3;
    const int bid = blockIdx.x;
    const int lid = (bid & 7) * cpx + (bid >> 3);
    const int mb  = lid % Mb;
    const int t1  = lid / Mb;
    const int nb  = t1 % Nb;
    const int g   = t1 / Nb;
    const int m0 = mb * 128, n0 = nb * 128;
    if (cnt != nullptr && m0 >= cnt[g]) return;

    const int tid = threadIdx.x, lane = tid & 63, w = tid >> 6;
    const int wr = w >> 1, wc = w & 1, ln = lane & 15, kg = lane >> 4;

    const short* Ag  = A  + (size_t)g * aStride + (size_t)m0 * 8;
    const short* Bg0 = B0 + (size_t)g * bStride + (size_t)n0 * 8;
    const short* Bg1 = nullptr;
    if constexpr (NMAT == 2) Bg1 = B1 + (size_t)g * bStride + (size_t)n0 * 8;

    const size_t aR8 = (size_t)aRpad * 8;   // shorts per A k-slab
    const size_t n8  = (size_t)N * 8;       // shorts per B k-slab

    // per-thread staging sources: chunk c0 = tid (slabs 0,1), c1 = tid+256 (2,3)
    const int srow = tid & 127, sslab = tid >> 7;
    const short* aS0 = Ag  + sslab * aR8 + srow * 8;
    const short* aS1 = Ag  + (2 + sslab) * aR8 + srow * 8;
    const short* bS00 = Bg0 + sslab * n8 + srow * 8;
    const short* bS01 = Bg0 + (2 + sslab) * n8 + srow * 8;
    const short* bS10 = nullptr, *bS11 = nullptr;
    if constexpr (NMAT == 2) {
        bS10 = Bg1 + sslab * n8 + srow * 8;
        bS11 = Bg1 + (2 + sslab) * n8 + srow * 8;
    }

    // wave-uniform LDS dest offsets (shorts): HW adds lane*16B
    const int dA0 = w * 512, dA1 = 2048 + w * 512;

    auto STG = [&](int buf, int ks) {
        const size_t ka = (size_t)ks * 4 * aR8;
        const size_t kb = (size_t)ks * 4 * n8;
        short* base = lds + buf * BUFS;
        GLDS16(aS0 + ka,  base + dA0);
        GLDS16(aS1 + ka,  base + dA1);
        GLDS16(bS00 + kb, base + 4096 + dA0);
        GLDS16(bS01 + kb, base + 4096 + dA1);
        if constexpr (NMAT == 2) {
            GLDS16(bS10 + kb, base + 8192 + dA0);
            GLDS16(bS11 + kb, base + 8192 + dA1);
        }
    };

    // frag read offsets (shorts): LDS per buf = [4 kg][128 row][8]
    const int aO = kg * 1024 + (wr * 64 + ln) * 8;
    const int bO = kg * 1024 + (wc * 64 + ln) * 8;

    f32x4 acc[NMAT][4][4] = {};

    const int nt = K / 32;
    STG(0, 0); STG(1, 1); STG(2, 2);
    int bb = 0;
    for (int ks = 0; ks < nt; ks++) {
        const int rem = nt - 1 - ks;
        if (rem >= 2) {
            if constexpr (NMAT == 2) asm volatile("s_waitcnt vmcnt(12)" ::: "memory");
            else                     asm volatile("s_waitcnt vmcnt(8)"  ::: "memory");
        } else if (rem == 1) {
            if constexpr (NMAT == 2) asm volatile("s_waitcnt vmcnt(6)" ::: "memory");
            else                     asm volatile("s_waitcnt vmcnt(4)" ::: "memory");
        } else {
            asm volatile("s_waitcnt vmcnt(0)" ::: "memory");
        }
        __builtin_amdgcn_s_barrier();
        __builtin_amdgcn_sched_barrier(0);

        const short* base = lds + bb * BUFS;
        s16x8 af[4];
#pragma unroll
        for (int m = 0; m < 4; m++)
            af[m] = *(const s16x8*)(base + aO + m * 128);
        s16x8 bf[NMAT][4];
#pragma unroll
        for (int mat = 0; mat < NMAT; mat++)
#pragma unroll
            for (int nf = 0; nf < 4; nf++)
                bf[mat][nf] = *(const s16x8*)(base + 4096 + mat * 4096 + bO + nf * 128);

        __builtin_amdgcn_s_setprio(1);
#pragma unroll
        for (int nf = 0; nf < 4; nf++)
#pragma unroll
            for (int m = 0; m < 4; m++)
#pragma unroll
                for (int mat = 0; mat < NMAT; mat++)
                    acc[mat][m][nf] = __builtin_amdgcn_mfma_f32_16x16x32_bf16(
                        af[m], bf[mat][nf], acc[mat][m][nf], 0, 0, 0);
        __builtin_amdgcn_s_setprio(0);
        __builtin_amdgcn_sched_barrier(0);
        __builtin_amdgcn_s_barrier();

        if (ks + 3 < nt) STG(bb, ks + 3);
        bb = (bb == 2) ? 0 : bb + 1;
    }

    // Epilogue. C/D: col = lane&15, row = (lane>>4)*4 + j  [m89-verified]
#pragma unroll
    for (int m = 0; m < 4; m++) {
#pragma unroll
        for (int nf = 0; nf < 4; nf++) {
            const int row = m0 + wr * 64 + m * 16 + kg * 4;
            const int col = n0 + wc * 64 + nf * 16 + ln;
#pragma unroll
            for (int j = 0; j < 4; j++) {
                if constexpr (NMAT == 2) {
                    float gv = acc[0][m][nf][j];
                    float uv = acc[1][m][nf][j];
                    float v = gv / (1.f + __expf(-gv)) * uv;
                    Out[(size_t)g * oStride + (size_t)(col >> 3) * (oRpad * 8) +
                        (size_t)(row + j) * 8 + (col & 7)] = f2bf(v);
                } else {
                    Out[(size_t)g * oStride + (size_t)(row + j) * N + col] =
                        f2bf(acc[0][m][nf][j]);
                }
            }
        }
    }
}

// ---------------- Combine: out = x + shared + sum_k w_k * expert_row --------
__global__ __launch_bounds__(256) void combine_kernel(
    const float* __restrict__ x, const short* __restrict__ shout,
    const short* __restrict__ eout, const int* __restrict__ dst,
    const float* __restrict__ wgt, float* __restrict__ out)
{
    const int t = blockIdx.x;
    const int d = threadIdx.x * 4;
    size_t o = (size_t)t * DIM + d;
    float4 xv = *(const float4*)(x + o);
    s16x4 sv = *(const s16x4*)(shout + o);
    float r0 = xv.x + bf2f(sv[0]);
    float r1 = xv.y + bf2f(sv[1]);
    float r2 = xv.z + bf2f(sv[2]);
    float r3 = xv.w + bf2f(sv[3]);
#pragma unroll
    for (int k = 0; k < 2; k++) {
        int di = dst[t * 2 + k];
        if (di >= 0) {
            float wv = wgt[t * 2 + k];
            s16x4 ev = *(const s16x4*)(eout + (size_t)di * DIM + d);
            r0 += wv * bf2f(ev[0]);
            r1 += wv * bf2f(ev[1]);
            r2 += wv * bf2f(ev[2]);
            r3 += wv * bf2f(ev[3]);
        }
    }
    float4 rv = {r0, r1, r2, r3};
    *(float4*)(out + o) = rv;
}

extern "C" void kernel_launch(void* const* d_in, const int* in_sizes, int n_in,
                              void* d_out, int out_size, void* d_ws, size_t ws_size,
                              hipStream_t stream)
{
    const float* x   = (const float*)d_in[0];
    const float* rw  = (const float*)d_in[1];
    const float* rb  = (const float*)d_in[2];
    const float* wg  = (const float*)d_in[3];
    const float* wu  = (const float*)d_in[4];
    const float* wd  = (const float*)d_in[5];
    const float* swg = (const float*)d_in[6];
    const float* swu = (const float*)d_in[7];
    const float* swd = (const float*)d_in[8];
    float* out = (float*)d_out;

    char* wp = (char*)d_ws;
    auto alloc = [&](size_t b) { char* p = wp; wp += (b + 255) & ~(size_t)255; return p; };
    int*   idx_flat = (int*)alloc((size_t)NK * 4);
    float* vals     = (float*)alloc((size_t)NK * 4);
    int*   dst      = (int*)alloc((size_t)NK * 4);
    float* wgt      = (float*)alloc((size_t)NK * 4);
    int*   cnt      = (int*)alloc(64);
    short* xb       = (short*)alloc((size_t)TOKENS * DIM * 2);          // chunk
    short* ex       = (short*)alloc((size_t)NEXP * RPAD * DIM * 2);     // chunk
    short* acte     = (short*)alloc((size_t)NEXP * RPAD * FDIM * 2);    // chunk
    short* acts     = (short*)alloc((size_t)TOKENS * FDIM * 2);         // chunk
    short* eout     = (short*)alloc((size_t)NEXP * RPAD * DIM * 2);     // canonical
    short* shout    = (short*)alloc((size_t)TOKENS * DIM * 2);          // canonical
    short* wgC      = (short*)alloc((size_t)NEXP * DIM * FDIM * 2);
    short* wuC      = (short*)alloc((size_t)NEXP * DIM * FDIM * 2);
    short* wdC      = (short*)alloc((size_t)NEXP * DIM * FDIM * 2);
    short* swgC     = (short*)alloc((size_t)DIM * FDIM * 2);
    short* swuC     = (short*)alloc((size_t)DIM * FDIM * 2);
    short* swdC     = (short*)alloc((size_t)DIM * FDIM * 2);

    // Weight reorder: fp32 [K][N] -> bf16 chunk [K/8][N][8]
    wchunk_kernel<<<dim3(FDIM / 128, DIM / 16, NEXP), 256, 0, stream>>>(wg,  wgC,  DIM,  FDIM);
    wchunk_kernel<<<dim3(FDIM / 128, DIM / 16, NEXP), 256, 0, stream>>>(wu,  wuC,  DIM,  FDIM);
    wchunk_kernel<<<dim3(DIM / 128, FDIM / 16, NEXP), 256, 0, stream>>>(wd,  wdC,  FDIM, DIM);
    wchunk_kernel<<<dim3(FDIM / 128, DIM / 16, 1),    256, 0, stream>>>(swg, swgC, DIM,  FDIM);
    wchunk_kernel<<<dim3(FDIM / 128, DIM / 16, 1),    256, 0, stream>>>(swu, swuC, DIM,  FDIM);
    wchunk_kernel<<<dim3(DIM / 128, FDIM / 16, 1),    256, 0, stream>>>(swd, swdC, FDIM, DIM);

    router_kernel<<<TOKENS / 16, 256, 0, stream>>>(x, rw, rb, idx_flat, vals);
    scan_kernel<<<1, 64, 0, stream>>>(idx_flat, vals, dst, wgt, cnt);
    xconv_kernel<<<TOKENS, 128, 0, stream>>>(x, xb);
    scatter_kernel<<<NK, 128, 0, stream>>>(x, dst, idx_flat, ex);

    // Gate+up fused (outputs in chunk layout for the down GEMM)
    gemm_kernel<2><<<3 * 11 * NEXP, 256, 0, stream>>>(
        ex, (long)RPAD * DIM, RPAD, wgC, wuC, (long)DIM * FDIM,
        acte, (long)RPAD * FDIM, RPAD, cnt, 3, 11, FDIM, DIM);
    gemm_kernel<2><<<16 * 11, 256, 0, stream>>>(
        xb, 0L, TOKENS, swgC, swuC, 0L,
        acts, 0L, TOKENS, nullptr, 16, 11, FDIM, DIM);

    // Down projections (canonical row-major outputs)
    gemm_kernel<1><<<3 * 8 * NEXP, 256, 0, stream>>>(
        acte, (long)RPAD * FDIM, RPAD, wdC, nullptr, (long)DIM * FDIM,
        eout, (long)RPAD * DIM, 0, cnt, 3, 8, DIM, FDIM);
    gemm_kernel<1><<<16 * 8, 256, 0, stream>>>(
        acts, 0L, TOKENS, swdC, nullptr, 0L,
        shout, 0L, 0, nullptr, 16, 8, DIM, FDIM);

    combine_kernel<<<TOKENS, 256, 0, stream>>>(x, shout, eout, dst, wgt, out);
}